// Round 4
// baseline (461.020 us; speedup 1.0000x reference)
//
#include <hip/hip_runtime.h>

#define HASH_BITS 19
#define HASH_SIZE (1u << HASH_BITS)
#define HASH_MASK (HASH_SIZE - 1)
#define EMPTY64 0xFFFFFFFFFFFFFFFFull
#define CH 256
#define PCH 32  // pairs per chunk in bucketed sparse kernels

typedef __attribute__((ext_vector_type(8))) short short8;
typedef __attribute__((ext_vector_type(4))) float floatx4;
typedef unsigned long long ull;

// split fp32 -> bf16 hi + bf16 lo (x ~= hi + lo, each RTN-even)
__device__ inline void bf16_split(float x, unsigned short& hi, unsigned short& lo) {
    unsigned u = __float_as_uint(x);
    unsigned r = u + (0x7FFFu + ((u >> 16) & 1u));
    hi = (unsigned short)(r >> 16);
    float hif = __uint_as_float(((unsigned)hi) << 16);
    float res = x - hif;
    unsigned v = __float_as_uint(res);
    unsigned rv = v + (0x7FFFu + ((v >> 16) & 1u));
    lo = (unsigned short)(rv >> 16);
}

__device__ inline void split8_pack(const float* xa, uint4& hv, uint4& lv) {
    unsigned short h[8], l[8];
#pragma unroll
    for (int q = 0; q < 8; ++q) bf16_split(xa[q], h[q], l[q]);
    hv.x = (unsigned)h[0] | ((unsigned)h[1] << 16);
    hv.y = (unsigned)h[2] | ((unsigned)h[3] << 16);
    hv.z = (unsigned)h[4] | ((unsigned)h[5] << 16);
    hv.w = (unsigned)h[6] | ((unsigned)h[7] << 16);
    lv.x = (unsigned)l[0] | ((unsigned)l[1] << 16);
    lv.y = (unsigned)l[2] | ((unsigned)l[3] << 16);
    lv.z = (unsigned)l[4] | ((unsigned)l[5] << 16);
    lv.w = (unsigned)l[6] | ((unsigned)l[7] << 16);
}

// ---------------- hash build: fused (key<<32 | idx) single-load table ----------------
__global__ void hash_insert_k(const int* __restrict__ coords, int n,
                              ull* __restrict__ tbl, unsigned* __restrict__ keys) {
    int i = blockIdx.x * blockDim.x + threadIdx.x;
    if (i >= n) return;
    unsigned cx = (unsigned)(coords[3 * i + 0] + 1);
    unsigned cy = (unsigned)(coords[3 * i + 1] + 1);
    unsigned cz = (unsigned)(coords[3 * i + 2] + 1);
    unsigned key = (cx * 258u + cy) * 258u + cz;
    keys[i] = key;
    ull e = ((ull)key << 32) | (unsigned)i;
    unsigned h = (key * 2654435761u) & HASH_MASK;
    while (true) {
        ull prev = atomicCAS(&tbl[h], EMPTY64, e);
        if (prev == EMPTY64) return;
        h = (h + 1) & HASH_MASK;
    }
}

// ---------------- neighbor pairs: 32 threads/point, one probe each ----------------
__global__ void neighbor_all_k(const unsigned* __restrict__ keys, int n,
                               const ull* __restrict__ tbl,
                               int2* __restrict__ buckets, int* __restrict__ kcount) {
    int t = blockIdx.x * blockDim.x + threadIdx.x;
    int i = t >> 5, k = t & 31;
    if (i >= n || k >= 27 || k == 13) return;  // center handled densely
    unsigned key = keys[i];
    int dx = k / 9 - 1, dy = (k / 3) % 3 - 1, dz = k % 3 - 1;
    unsigned nk = (unsigned)((int)key + (dx * 258 + dy) * 258 + dz);
    unsigned h = (nk * 2654435761u) & HASH_MASK;
    while (true) {
        ull e = tbl[h];
        unsigned hi = (unsigned)(e >> 32);
        if (hi == nk) {
            int j = (int)(e & 0xFFFFFFFFu);
            int pos = atomicAdd(&kcount[k], 1);
            buckets[(size_t)k * n + pos] = make_int2(i, j);
            return;
        }
        if (e == EMPTY64) return;
        h = (h + 1) & HASH_MASK;
    }
}

// ---------------- chunk descriptors: (start, k<<8|len) per <=PCH-pair chunk ----------------
__global__ void chunk_desc_k(const int* __restrict__ kcount, int n,
                             int2* __restrict__ desc, int* __restrict__ nchunks) {
    __shared__ int offs[28];
    int t = threadIdx.x;
    if (t == 0) {
        int acc = 0;
        for (int k = 0; k < 27; ++k) { offs[k] = acc; acc += (kcount[k] + PCH - 1) / PCH; }
        offs[27] = acc;
        *nchunks = acc;
    }
    __syncthreads();
    if (t < 27) {
        int cnt = kcount[t];
        int o = offs[t];
        for (int c = 0; c * PCH < cnt; ++c) {
            int len = min(PCH, cnt - c * PCH);
            desc[o + c] = make_int2(t * n + c * PCH, (t << 8) | len);
        }
    }
}

// ---------------- pre-split ALL 27 W slices into MFMA-fragment-ordered bf16 image ----------
// image layout: [k(27)][kk(8)][nt(16)][lane(64)][j(8)] shorts
// cin = kk*32 + (lane>>4)*8 + j,  cout = nt*16 + (lane&15)
__global__ void prep_w_all_k(const float* __restrict__ W, unsigned short* __restrict__ Whi,
                             unsigned short* __restrict__ Wlo) {
    int tt = blockIdx.x * 256 + threadIdx.x;
    if (tt >= 27 * 65536) return;
    int k = tt >> 16, rem = tt & 65535, cin = rem >> 8, cout = rem & 255;
    float w = W[tt];
    unsigned short hb, lb;
    bf16_split(w, hb, lb);
    int kk = cin >> 5, kg = (cin >> 3) & 3, j = cin & 7, nt = cout >> 4, lc = cout & 15;
    size_t idx = ((((size_t)(k * 8 + kk) * 16 + nt) * 64) + kg * 16 + lc) * 8 + j;
    Whi[idx] = hb;
    Wlo[idx] = lb;
}

// ---------------- layer 1: Cin=2 -> 256, dense center ----------------
__global__ void dense1_k(const float* __restrict__ x, const float* __restrict__ Wc,
                         float* __restrict__ out, int n) {
    int t = blockIdx.x * blockDim.x + threadIdx.x;
    if (t >= n * CH) return;
    int i = t >> 8, co = t & 255;
    float2 xv = *reinterpret_cast<const float2*>(x + 2 * i);
    out[t] = fmaf(xv.x, Wc[co], xv.y * Wc[CH + co]);
}

__global__ void sparse1b_k(const float* __restrict__ feats, const float* __restrict__ W1,
                           float* __restrict__ out, const int2* __restrict__ buckets,
                           const int2* __restrict__ desc, const int* __restrict__ nchunks) {
    __shared__ float xs[PCH][2];
    __shared__ int ii[PCH];
    int nc = *nchunks;
    int t = threadIdx.x;
    for (int m = blockIdx.x; m < nc; m += gridDim.x) {
        int2 d = desc[m];
        int k = d.y >> 8, len = d.y & 255;
        if (t < PCH) {
            if (t < len) {
                int2 pr = buckets[d.x + t];
                ii[t] = pr.x;
                xs[t][0] = feats[2 * pr.y];
                xs[t][1] = feats[2 * pr.y + 1];
            } else {
                ii[t] = -1;
                xs[t][0] = 0.f; xs[t][1] = 0.f;
            }
        }
        __syncthreads();
        const float* Wk = W1 + (size_t)k * 2 * CH;
        float w0 = Wk[t], w1 = Wk[CH + t];
#pragma unroll
        for (int p = 0; p < PCH; ++p) {
            int i = ii[p];
            if (i >= 0) atomicAdd(&out[(size_t)i * CH + t], fmaf(xs[p][0], w0, xs[p][1] * w1));
        }
        __syncthreads();
    }
}

// ---------------- mid layers dense center: no-LDS, no-barrier streaming MFMA ----------------
// A fragments loaded per-lane directly from x (fp32, split in-register);
// B fragments loaded global->VGPR from the pre-ordered image (each used by one wave only).
__global__ __launch_bounds__(256) void dense_mid_mfma_k(
        const float* __restrict__ x,
        const unsigned short* __restrict__ Whi,
        const unsigned short* __restrict__ Wlo,
        float* __restrict__ out, int n) {
    int t = threadIdx.x;
    int wid = t >> 6, lane = t & 63;
    int i0 = blockIdx.x * 64;
    int rl = lane & 15, cb = (lane >> 4) * 8;

    floatx4 acc[4][4];
#pragma unroll
    for (int a = 0; a < 4; ++a)
#pragma unroll
        for (int b = 0; b < 4; ++b) acc[a][b] = floatx4{0.f, 0.f, 0.f, 0.f};

    const float* arow[4];
    float okf[4];
#pragma unroll
    for (int mt = 0; mt < 4; ++mt) {
        int row = i0 + mt * 16 + rl;
        okf[mt] = (row < n) ? 1.f : 0.f;
        arow[mt] = x + (size_t)min(row, n - 1) * CH + cb;
    }

    for (int kk = 0; kk < 8; ++kk) {
        short8 bh[4], bl[4];
#pragma unroll
        for (int q = 0; q < 4; ++q) {
            size_t off = ((size_t)kk * 16 + wid * 4 + q) * 512 + (size_t)lane * 8;
            bh[q] = *(const short8*)&Whi[off];
            bl[q] = *(const short8*)&Wlo[off];
        }
#pragma unroll
        for (int mt = 0; mt < 4; ++mt) {
            floatx4 v0 = *(const floatx4*)(arow[mt] + kk * 32);
            floatx4 v1 = *(const floatx4*)(arow[mt] + kk * 32 + 4);
            float xa[8];
            xa[0] = v0.x * okf[mt]; xa[1] = v0.y * okf[mt];
            xa[2] = v0.z * okf[mt]; xa[3] = v0.w * okf[mt];
            xa[4] = v1.x * okf[mt]; xa[5] = v1.y * okf[mt];
            xa[6] = v1.z * okf[mt]; xa[7] = v1.w * okf[mt];
            uint4 hv, lv;
            split8_pack(xa, hv, lv);
            short8 ah, al;
            *(uint4*)&ah = hv;
            *(uint4*)&al = lv;
#pragma unroll
            for (int q = 0; q < 4; ++q) {
                acc[mt][q] = __builtin_amdgcn_mfma_f32_16x16x32_bf16(ah, bh[q], acc[mt][q], 0, 0, 0);
                acc[mt][q] = __builtin_amdgcn_mfma_f32_16x16x32_bf16(al, bh[q], acc[mt][q], 0, 0, 0);
                acc[mt][q] = __builtin_amdgcn_mfma_f32_16x16x32_bf16(ah, bl[q], acc[mt][q], 0, 0, 0);
            }
        }
    }
    // epilogue: D row=(lane>>4)*4+reg, col=lane&15
    int r0 = (lane >> 4) * 4, c0 = lane & 15;
#pragma unroll
    for (int mt = 0; mt < 4; ++mt)
#pragma unroll
        for (int r = 0; r < 4; ++r) {
            int row = i0 + mt * 16 + r0 + r;
            if (row < n) {
#pragma unroll
                for (int q = 0; q < 4; ++q)
                    out[(size_t)row * CH + wid * 64 + q * 16 + c0] = acc[mt][q][r];
            }
        }
}

// ---------------- mid layers sparse: 32 gathered rows per chunk, 3-pass MFMA ----------------
__global__ __launch_bounds__(256) void sparse_mid_mfma_k(
        const float* __restrict__ x,
        const unsigned short* __restrict__ Whi,
        const unsigned short* __restrict__ Wlo,
        float* __restrict__ out, const int2* __restrict__ buckets,
        const int2* __restrict__ desc, const int* __restrict__ nchunks) {
    // A image: [kk(8)][mt(2)][lane(64)][j(8)]
    __shared__ unsigned short As_hi[8192];
    __shared__ unsigned short As_lo[8192];
    __shared__ int ii[PCH];
    int nc = *nchunks;
    int t = threadIdx.x;
    int wid = t >> 6, lane = t & 63;
    int r = t >> 3, kk0 = t & 7;          // 8 threads per gathered row
    int mt_s = r >> 4, rl = r & 15;
    for (int m = blockIdx.x; m < nc; m += gridDim.x) {
        int2 d = desc[m];
        int k = d.y >> 8, len = d.y & 255;
        // ---- stage A (full K=256 for 32 rows), split hi/lo ----
        if (r < len) {
            int2 pr = buckets[d.x + r];
            if (kk0 == 0) ii[r] = pr.x;
            const float* src = x + (size_t)pr.y * CH + kk0 * 32;
#pragma unroll
            for (int kg = 0; kg < 4; ++kg) {
                float xa[8];
                floatx4 v0 = *(const floatx4*)(src + kg * 8);
                floatx4 v1 = *(const floatx4*)(src + kg * 8 + 4);
                xa[0] = v0.x; xa[1] = v0.y; xa[2] = v0.z; xa[3] = v0.w;
                xa[4] = v1.x; xa[5] = v1.y; xa[6] = v1.z; xa[7] = v1.w;
                uint4 hv, lv;
                split8_pack(xa, hv, lv);
                int ab = ((kk0 * 2 + mt_s) * 64 + kg * 16 + rl) * 8;
                *(uint4*)&As_hi[ab] = hv;
                *(uint4*)&As_lo[ab] = lv;
            }
        } else {
            if (kk0 == 0) ii[r] = -1;
            uint4 z = {0, 0, 0, 0};
#pragma unroll
            for (int kg = 0; kg < 4; ++kg) {
                int ab = ((kk0 * 2 + mt_s) * 64 + kg * 16 + rl) * 8;
                *(uint4*)&As_hi[ab] = z;
                *(uint4*)&As_lo[ab] = z;
            }
        }
        __syncthreads();
        floatx4 acc[2][4];
#pragma unroll
        for (int a = 0; a < 2; ++a)
#pragma unroll
            for (int b = 0; b < 4; ++b) acc[a][b] = floatx4{0.f, 0.f, 0.f, 0.f};
        for (int kk = 0; kk < 8; ++kk) {
            short8 ah0 = *(const short8*)&As_hi[((kk * 2 + 0) * 64 + lane) * 8];
            short8 al0 = *(const short8*)&As_lo[((kk * 2 + 0) * 64 + lane) * 8];
            short8 ah1 = *(const short8*)&As_hi[((kk * 2 + 1) * 64 + lane) * 8];
            short8 al1 = *(const short8*)&As_lo[((kk * 2 + 1) * 64 + lane) * 8];
#pragma unroll
            for (int q = 0; q < 4; ++q) {
                int nt = wid * 4 + q;
                size_t off = (((size_t)(k * 8 + kk) * 16 + nt) * 64 + lane) * 8;
                short8 bh = *(const short8*)&Whi[off];   // B direct global->VGPR (used once)
                short8 bl = *(const short8*)&Wlo[off];
                acc[0][q] = __builtin_amdgcn_mfma_f32_16x16x32_bf16(ah0, bh, acc[0][q], 0, 0, 0);
                acc[0][q] = __builtin_amdgcn_mfma_f32_16x16x32_bf16(al0, bh, acc[0][q], 0, 0, 0);
                acc[0][q] = __builtin_amdgcn_mfma_f32_16x16x32_bf16(ah0, bl, acc[0][q], 0, 0, 0);
                acc[1][q] = __builtin_amdgcn_mfma_f32_16x16x32_bf16(ah1, bh, acc[1][q], 0, 0, 0);
                acc[1][q] = __builtin_amdgcn_mfma_f32_16x16x32_bf16(al1, bh, acc[1][q], 0, 0, 0);
                acc[1][q] = __builtin_amdgcn_mfma_f32_16x16x32_bf16(ah1, bl, acc[1][q], 0, 0, 0);
            }
        }
        // ---- epilogue: atomic accumulate ----
        int r0 = (lane >> 4) * 4, c0 = lane & 15;
#pragma unroll
        for (int mt = 0; mt < 2; ++mt)
#pragma unroll
            for (int rr = 0; rr < 4; ++rr) {
                int row = mt * 16 + r0 + rr;
                int i = ii[row];
                if (i >= 0) {
#pragma unroll
                    for (int q = 0; q < 4; ++q)
                        atomicAdd(&out[(size_t)i * CH + wid * 64 + q * 16 + c0], acc[mt][q][rr]);
                }
            }
        __syncthreads();
    }
}

// ---------------- layer 4: 256 -> 2 ----------------
__device__ inline float wave_sum(float v) {
    for (int off = 32; off; off >>= 1) v += __shfl_xor(v, off);
    return v;
}

__global__ void dense4_k(const float* __restrict__ x, const float* __restrict__ Wc,
                         float* __restrict__ out, int n) {
    int wid = threadIdx.x >> 6, lane = threadIdx.x & 63;
    int i = blockIdx.x * 4 + wid;
    if (i >= n) return;
    floatx4 xv = *reinterpret_cast<const floatx4*>(x + (size_t)i * CH + lane * 4);
    floatx4 w0 = *reinterpret_cast<const floatx4*>(Wc + lane * 8);
    floatx4 w1 = *reinterpret_cast<const floatx4*>(Wc + lane * 8 + 4);
    float a0 = xv.x * w0.x + xv.y * w0.z + xv.z * w1.x + xv.w * w1.z;
    float a1 = xv.x * w0.y + xv.y * w0.w + xv.z * w1.y + xv.w * w1.w;
    a0 = wave_sum(a0);
    a1 = wave_sum(a1);
    if (lane == 0) { out[2 * i] = a0; out[2 * i + 1] = a1; }
}

__global__ void sparse4b_k(const float* __restrict__ x, const float* __restrict__ W4,
                           float* __restrict__ out, const int2* __restrict__ buckets,
                           const int2* __restrict__ desc, const int* __restrict__ nchunks) {
    int nc = *nchunks;
    int wid = threadIdx.x >> 6, lane = threadIdx.x & 63;
    for (int m = blockIdx.x; m < nc; m += gridDim.x) {
        int2 d = desc[m];
        int k = d.y >> 8, len = d.y & 255;
        const float* Wk = W4 + (size_t)k * CH * 2;
        floatx4 w0 = *reinterpret_cast<const floatx4*>(Wk + lane * 8);
        floatx4 w1 = *reinterpret_cast<const floatx4*>(Wk + lane * 8 + 4);
        for (int p = wid; p < len; p += 4) {
            int2 pr = buckets[d.x + p];
            floatx4 xv = *reinterpret_cast<const floatx4*>(x + (size_t)pr.y * CH + lane * 4);
            float a0 = xv.x * w0.x + xv.y * w0.z + xv.z * w1.x + xv.w * w1.z;
            float a1 = xv.x * w0.y + xv.y * w0.w + xv.z * w1.y + xv.w * w1.w;
            a0 = wave_sum(a0);
            a1 = wave_sum(a1);
            if (lane == 0) {
                atomicAdd(&out[2 * pr.x], a0);
                atomicAdd(&out[2 * pr.x + 1], a1);
            }
        }
    }
}

extern "C" void kernel_launch(void* const* d_in, const int* in_sizes, int n_in,
                              void* d_out, int out_size, void* d_ws, size_t ws_size,
                              hipStream_t stream) {
    const int* coords = (const int*)d_in[0];
    const float* feats = (const float*)d_in[1];
    const float* W1 = (const float*)d_in[2];
    const float* W2 = (const float*)d_in[3];
    const float* W3 = (const float*)d_in[4];
    const float* W4 = (const float*)d_in[5];
    float* out = (float*)d_out;
    int n = in_sizes[0] / 3;

    char* ws = (char*)d_ws;
    auto alloc = [&](size_t bytes) -> void* {
        void* p = (void*)ws;
        ws += (bytes + 255) & ~(size_t)255;
        return p;
    };
    ull* tbl = (ull*)alloc((size_t)HASH_SIZE * 8);
    unsigned* keys = (unsigned*)alloc((size_t)n * 4);
    int* kcount = (int*)alloc(27 * 4);
    int* nchunks = (int*)alloc(4);
    int ndesc = 27 * ((n + PCH - 1) / PCH);
    int2* desc = (int2*)alloc(sizeof(int2) * (size_t)ndesc);
    int2* buckets = (int2*)alloc(sizeof(int2) * 27 * (size_t)n);
    unsigned short* Whi2 = (unsigned short*)alloc((size_t)27 * 65536 * 2);
    unsigned short* Wlo2 = (unsigned short*)alloc((size_t)27 * 65536 * 2);
    unsigned short* Whi3 = (unsigned short*)alloc((size_t)27 * 65536 * 2);
    unsigned short* Wlo3 = (unsigned short*)alloc((size_t)27 * 65536 * 2);
    float* x1 = (float*)alloc((size_t)n * CH * 4);
    float* x2 = (float*)alloc((size_t)n * CH * 4);

    hipMemsetAsync(tbl, 0xFF, (size_t)HASH_SIZE * 8, stream);
    hipMemsetAsync(kcount, 0, 27 * 4, stream);

    hash_insert_k<<<(n + 255) / 256, 256, 0, stream>>>(coords, n, tbl, keys);
    neighbor_all_k<<<(n * 32 + 255) / 256, 256, 0, stream>>>(keys, n, tbl, buckets, kcount);
    chunk_desc_k<<<1, 256, 0, stream>>>(kcount, n, desc, nchunks);
    prep_w_all_k<<<(27 * 65536) / 256, 256, 0, stream>>>(W2, Whi2, Wlo2);
    prep_w_all_k<<<(27 * 65536) / 256, 256, 0, stream>>>(W3, Whi3, Wlo3);

    int mtiles = (n + 63) / 64;

    // layer 1: 2 -> 256
    dense1_k<<<(n * CH + 255) / 256, 256, 0, stream>>>(feats, W1 + 13 * 2 * CH, x1, n);
    sparse1b_k<<<1024, 256, 0, stream>>>(feats, W1, x1, buckets, desc, nchunks);

    // layer 2: 256 -> 256
    dense_mid_mfma_k<<<mtiles, 256, 0, stream>>>(x1, Whi2 + (size_t)13 * 65536,
                                                 Wlo2 + (size_t)13 * 65536, x2, n);
    sparse_mid_mfma_k<<<512, 256, 0, stream>>>(x1, Whi2, Wlo2, x2, buckets, desc, nchunks);

    // layer 3: 256 -> 256
    dense_mid_mfma_k<<<mtiles, 256, 0, stream>>>(x2, Whi3 + (size_t)13 * 65536,
                                                 Wlo3 + (size_t)13 * 65536, x1, n);
    sparse_mid_mfma_k<<<512, 256, 0, stream>>>(x2, Whi3, Wlo3, x1, buckets, desc, nchunks);

    // layer 4: 256 -> 2
    dense4_k<<<(n + 3) / 4, 256, 0, stream>>>(x1, W4 + 13 * CH * 2, out, n);
    sparse4b_k<<<512, 256, 0, stream>>>(x1, W4, out, buckets, desc, nchunks);
}

// Round 5
// 389.852 us; speedup vs baseline: 1.1825x; 1.1825x over previous
//
#include <hip/hip_runtime.h>

#define HASH_BITS 19
#define HASH_SIZE (1u << HASH_BITS)
#define HASH_MASK (HASH_SIZE - 1)
#define EMPTY64 0xFFFFFFFFFFFFFFFFull
#define CH 256
#define PCH 32  // pairs per chunk in bucketed sparse kernels
#define BM_WORDS 536704  // ceil(258^3 / 32), padded

typedef __attribute__((ext_vector_type(8))) short short8;
typedef __attribute__((ext_vector_type(4))) float floatx4;
typedef unsigned long long ull;

// split fp32 -> bf16 hi + bf16 lo (x ~= hi + lo, each RTN-even)
__device__ inline void bf16_split(float x, unsigned short& hi, unsigned short& lo) {
    unsigned u = __float_as_uint(x);
    unsigned r = u + (0x7FFFu + ((u >> 16) & 1u));
    hi = (unsigned short)(r >> 16);
    float hif = __uint_as_float(((unsigned)hi) << 16);
    float res = x - hif;
    unsigned v = __float_as_uint(res);
    unsigned rv = v + (0x7FFFu + ((v >> 16) & 1u));
    lo = (unsigned short)(rv >> 16);
}

__device__ inline void split8_pack(const float* xa, uint4& hv, uint4& lv) {
    unsigned short h[8], l[8];
#pragma unroll
    for (int q = 0; q < 8; ++q) bf16_split(xa[q], h[q], l[q]);
    hv.x = (unsigned)h[0] | ((unsigned)h[1] << 16);
    hv.y = (unsigned)h[2] | ((unsigned)h[3] << 16);
    hv.z = (unsigned)h[4] | ((unsigned)h[5] << 16);
    hv.w = (unsigned)h[6] | ((unsigned)h[7] << 16);
    lv.x = (unsigned)l[0] | ((unsigned)l[1] << 16);
    lv.y = (unsigned)l[2] | ((unsigned)l[3] << 16);
    lv.z = (unsigned)l[4] | ((unsigned)l[5] << 16);
    lv.w = (unsigned)l[6] | ((unsigned)l[7] << 16);
}

// ---------------- hash build: fused (key<<32 | idx) single-load table ----------------
__global__ void hash_insert_k(const int* __restrict__ coords, int n,
                              ull* __restrict__ tbl, unsigned* __restrict__ keys,
                              unsigned* __restrict__ bm) {
    int i = blockIdx.x * blockDim.x + threadIdx.x;
    if (i >= n) return;
    unsigned cx = (unsigned)(coords[3 * i + 0] + 1);
    unsigned cy = (unsigned)(coords[3 * i + 1] + 1);
    unsigned cz = (unsigned)(coords[3 * i + 2] + 1);
    unsigned key = (cx * 258u + cy) * 258u + cz;
    keys[i] = key;
    atomicOr(&bm[key >> 5], 1u << (key & 31));
    ull e = ((ull)key << 32) | (unsigned)i;
    unsigned h = (key * 2654435761u) & HASH_MASK;
    while (true) {
        ull prev = atomicCAS(&tbl[h], EMPTY64, e);
        if (prev == EMPTY64) return;
        h = (h + 1) & HASH_MASK;
    }
}

// ---------------- neighbor pairs: bitmap prefilter, 9 threads/point ----------------
__global__ void neighbor_bm_k(const unsigned* __restrict__ keys, int n,
                              const unsigned* __restrict__ bm,
                              const ull* __restrict__ tbl,
                              int2* __restrict__ buckets, int* __restrict__ kcount) {
    int t = blockIdx.x * blockDim.x + threadIdx.x;
    if (t >= n * 9) return;
    int i = t / 9, r = t - i * 9;            // r = (dx+1)*3 + (dy+1)
    unsigned key = keys[i];
    int base = (int)key + ((r / 3 - 1) * 258 + (r % 3 - 1)) * 258;
    // three candidate keys base-1, base, base+1 (dz=-1,0,1); bits mostly in one word
    unsigned bA = base - 1, bB = base, bC = base + 1;
    unsigned hit0 = (bm[bA >> 5] >> (bA & 31)) & 1u;
    unsigned hit1 = (bm[bB >> 5] >> (bB & 31)) & 1u;
    unsigned hit2 = (bm[bC >> 5] >> (bC & 31)) & 1u;
#pragma unroll
    for (int dz = -1; dz <= 1; ++dz) {
        if (r == 4 && dz == 0) continue;     // center handled densely
        unsigned hit = dz < 0 ? hit0 : (dz == 0 ? hit1 : hit2);
        if (!hit) continue;
        unsigned nk = (unsigned)(base + dz);
        unsigned h = (nk * 2654435761u) & HASH_MASK;
        int j = -1;
        while (true) {
            ull e = tbl[h];
            if ((unsigned)(e >> 32) == nk) { j = (int)(e & 0xFFFFFFFFu); break; }
            if (e == EMPTY64) break;
            h = (h + 1) & HASH_MASK;
        }
        if (j >= 0) {
            int kk = 3 * r + dz + 1;
            int pos = atomicAdd(&kcount[kk], 1);
            buckets[(size_t)kk * n + pos] = make_int2(i, j);
        }
    }
}

// ---------------- chunk descriptors: (start, k<<8|len) per <=PCH-pair chunk ----------------
__global__ void chunk_desc_k(const int* __restrict__ kcount, int n,
                             int2* __restrict__ desc, int* __restrict__ nchunks) {
    __shared__ int offs[28];
    int t = threadIdx.x;
    if (t == 0) {
        int acc = 0;
        for (int k = 0; k < 27; ++k) { offs[k] = acc; acc += (kcount[k] + PCH - 1) / PCH; }
        offs[27] = acc;
        *nchunks = acc;
    }
    __syncthreads();
    if (t < 27) {
        int cnt = kcount[t];
        int o = offs[t];
        for (int c = 0; c * PCH < cnt; ++c) {
            int len = min(PCH, cnt - c * PCH);
            desc[o + c] = make_int2(t * n + c * PCH, (t << 8) | len);
        }
    }
}

// ---------------- pre-split ALL 27 W slices into MFMA-fragment-ordered bf16 image ----------
// image layout: [k(27)][kk(8)][nt(16)][lane(64)][j(8)] shorts
// cin = kk*32 + (lane>>4)*8 + j,  cout = nt*16 + (lane&15)
__global__ void prep_w_all_k(const float* __restrict__ W, unsigned short* __restrict__ Whi,
                             unsigned short* __restrict__ Wlo) {
    int tt = blockIdx.x * 256 + threadIdx.x;
    if (tt >= 27 * 65536) return;
    int k = tt >> 16, rem = tt & 65535, cin = rem >> 8, cout = rem & 255;
    float w = W[tt];
    unsigned short hb, lb;
    bf16_split(w, hb, lb);
    int kk = cin >> 5, kg = (cin >> 3) & 3, j = cin & 7, nt = cout >> 4, lc = cout & 15;
    size_t idx = ((((size_t)(k * 8 + kk) * 16 + nt) * 64) + kg * 16 + lc) * 8 + j;
    Whi[idx] = hb;
    Wlo[idx] = lb;
}

// ---------------- layer 1: Cin=2 -> 256, dense center ----------------
__global__ void dense1_k(const float* __restrict__ x, const float* __restrict__ Wc,
                         float* __restrict__ out, int n) {
    int t = blockIdx.x * blockDim.x + threadIdx.x;
    if (t >= n * CH) return;
    int i = t >> 8, co = t & 255;
    float2 xv = *reinterpret_cast<const float2*>(x + 2 * i);
    out[t] = fmaf(xv.x, Wc[co], xv.y * Wc[CH + co]);
}

__global__ void sparse1b_k(const float* __restrict__ feats, const float* __restrict__ W1,
                           float* __restrict__ out, const int2* __restrict__ buckets,
                           const int2* __restrict__ desc, const int* __restrict__ nchunks) {
    __shared__ float xs[PCH][2];
    __shared__ int ii[PCH];
    int nc = *nchunks;
    int t = threadIdx.x;
    for (int m = blockIdx.x; m < nc; m += gridDim.x) {
        int2 d = desc[m];
        int k = d.y >> 8, len = d.y & 255;
        if (t < PCH) {
            if (t < len) {
                int2 pr = buckets[d.x + t];
                ii[t] = pr.x;
                xs[t][0] = feats[2 * pr.y];
                xs[t][1] = feats[2 * pr.y + 1];
            } else {
                ii[t] = -1;
                xs[t][0] = 0.f; xs[t][1] = 0.f;
            }
        }
        __syncthreads();
        const float* Wk = W1 + (size_t)k * 2 * CH;
        float w0 = Wk[t], w1 = Wk[CH + t];
#pragma unroll
        for (int p = 0; p < PCH; ++p) {
            int i = ii[p];
            if (i >= 0) atomicAdd(&out[(size_t)i * CH + t], fmaf(xs[p][0], w0, xs[p][1] * w1));
        }
        __syncthreads();
    }
}

// ---------------- mid layers dense center: A-LDS dbuf + B reg-dbuf, 1 barrier/kk ----------
__global__ __launch_bounds__(256, 2) void dense_mid_mfma_k(
        const float* __restrict__ x,
        const unsigned short* __restrict__ Whi,
        const unsigned short* __restrict__ Wlo,
        float* __restrict__ out, int n) {
    __shared__ unsigned short AsH0[2048], AsL0[2048];  // [mt(4)][flane(64)][j(8)]
    __shared__ unsigned short AsH1[2048], AsL1[2048];
    int t = threadIdx.x;
    int wid = t >> 6, lane = t & 63;
    int i0 = blockIdx.x * 64;

    floatx4 acc[4][4];
#pragma unroll
    for (int a = 0; a < 4; ++a)
#pragma unroll
        for (int b = 0; b < 4; ++b) acc[a][b] = floatx4{0.f, 0.f, 0.f, 0.f};

    // A staging role: thread t stages row ar, k-group akg
    int ar = t >> 2, akg = t & 3;
    int abase = ((ar >> 4) * 64 + akg * 16 + (ar & 15)) * 8;
    int rowi = i0 + ar;
    float okf = (rowi < n) ? 1.f : 0.f;
    const float* xrow = x + (size_t)min(rowi, n - 1) * CH + akg * 8;

    short8 Bh0[4], Bl0[4], Bh1[4], Bl1[4];

    auto loadB = [&](int kk, short8* Bh, short8* Bl) {
#pragma unroll
        for (int q = 0; q < 4; ++q) {
            size_t off = (((size_t)kk * 16 + wid * 4 + q) * 64 + lane) * 8;
            Bh[q] = *(const short8*)&Whi[off];
            Bl[q] = *(const short8*)&Wlo[off];
        }
    };
    auto stageA = [&](int kk, unsigned short* AH, unsigned short* AL) {
        floatx4 v0 = *(const floatx4*)(xrow + kk * 32);
        floatx4 v1 = *(const floatx4*)(xrow + kk * 32 + 4);
        float xa[8];
        xa[0] = v0.x * okf; xa[1] = v0.y * okf; xa[2] = v0.z * okf; xa[3] = v0.w * okf;
        xa[4] = v1.x * okf; xa[5] = v1.y * okf; xa[6] = v1.z * okf; xa[7] = v1.w * okf;
        uint4 hv, lv;
        split8_pack(xa, hv, lv);
        *(uint4*)&AH[abase] = hv;
        *(uint4*)&AL[abase] = lv;
    };
    auto compute = [&](unsigned short* AH, unsigned short* AL, short8* Bh, short8* Bl) {
#pragma unroll
        for (int mt = 0; mt < 4; ++mt) {
            short8 ah = *(const short8*)&AH[(mt * 64 + lane) * 8];
            short8 al = *(const short8*)&AL[(mt * 64 + lane) * 8];
#pragma unroll
            for (int q = 0; q < 4; ++q) {
                acc[mt][q] = __builtin_amdgcn_mfma_f32_16x16x32_bf16(ah, Bh[q], acc[mt][q], 0, 0, 0);
                acc[mt][q] = __builtin_amdgcn_mfma_f32_16x16x32_bf16(al, Bh[q], acc[mt][q], 0, 0, 0);
                acc[mt][q] = __builtin_amdgcn_mfma_f32_16x16x32_bf16(ah, Bl[q], acc[mt][q], 0, 0, 0);
            }
        }
    };

    // prologue: B(0) + A(0)
    loadB(0, Bh0, Bl0);
    stageA(0, AsH0, AsL0);
    __syncthreads();

#pragma unroll
    for (int kk2 = 0; kk2 < 8; kk2 += 2) {
        // even step: cur = buf0, next = buf1
        if (kk2 + 1 < 8) {
            loadB(kk2 + 1, Bh1, Bl1);
            stageA(kk2 + 1, AsH1, AsL1);
        }
        compute(AsH0, AsL0, Bh0, Bl0);
        __syncthreads();
        // odd step: cur = buf1, next = buf0
        if (kk2 + 2 < 8) {
            loadB(kk2 + 2, Bh0, Bl0);
            stageA(kk2 + 2, AsH0, AsL0);
        }
        compute(AsH1, AsL1, Bh1, Bl1);
        __syncthreads();
    }

    // epilogue: D row=(lane>>4)*4+reg, col=lane&15
    int r0 = (lane >> 4) * 4, c0 = lane & 15;
#pragma unroll
    for (int mt = 0; mt < 4; ++mt)
#pragma unroll
        for (int r = 0; r < 4; ++r) {
            int row = i0 + mt * 16 + r0 + r;
            if (row < n) {
#pragma unroll
                for (int q = 0; q < 4; ++q)
                    out[(size_t)row * CH + wid * 64 + q * 16 + c0] = acc[mt][q][r];
            }
        }
}

// ---------------- mid layers sparse: 32 gathered rows per chunk, 3-pass MFMA ----------------
__global__ __launch_bounds__(256) void sparse_mid_mfma_k(
        const float* __restrict__ x,
        const unsigned short* __restrict__ Whi,
        const unsigned short* __restrict__ Wlo,
        float* __restrict__ out, const int2* __restrict__ buckets,
        const int2* __restrict__ desc, const int* __restrict__ nchunks) {
    // A image: [kk(8)][mt(2)][lane(64)][j(8)]
    __shared__ unsigned short As_hi[8192];
    __shared__ unsigned short As_lo[8192];
    __shared__ int ii[PCH];
    int nc = *nchunks;
    int t = threadIdx.x;
    int wid = t >> 6, lane = t & 63;
    int r = t >> 3, kk0 = t & 7;          // 8 threads per gathered row
    int mt_s = r >> 4, rl = r & 15;
    for (int m = blockIdx.x; m < nc; m += gridDim.x) {
        int2 d = desc[m];
        int k = d.y >> 8, len = d.y & 255;
        // ---- stage A (full K=256 for 32 rows), split hi/lo ----
        if (r < len) {
            int2 pr = buckets[d.x + r];
            if (kk0 == 0) ii[r] = pr.x;
            const float* src = x + (size_t)pr.y * CH + kk0 * 32;
#pragma unroll
            for (int kg = 0; kg < 4; ++kg) {
                float xa[8];
                floatx4 v0 = *(const floatx4*)(src + kg * 8);
                floatx4 v1 = *(const floatx4*)(src + kg * 8 + 4);
                xa[0] = v0.x; xa[1] = v0.y; xa[2] = v0.z; xa[3] = v0.w;
                xa[4] = v1.x; xa[5] = v1.y; xa[6] = v1.z; xa[7] = v1.w;
                uint4 hv, lv;
                split8_pack(xa, hv, lv);
                int ab = ((kk0 * 2 + mt_s) * 64 + kg * 16 + rl) * 8;
                *(uint4*)&As_hi[ab] = hv;
                *(uint4*)&As_lo[ab] = lv;
            }
        } else {
            if (kk0 == 0) ii[r] = -1;
            uint4 z = {0, 0, 0, 0};
#pragma unroll
            for (int kg = 0; kg < 4; ++kg) {
                int ab = ((kk0 * 2 + mt_s) * 64 + kg * 16 + rl) * 8;
                *(uint4*)&As_hi[ab] = z;
                *(uint4*)&As_lo[ab] = z;
            }
        }
        __syncthreads();
        floatx4 acc[2][4];
#pragma unroll
        for (int a = 0; a < 2; ++a)
#pragma unroll
            for (int b = 0; b < 4; ++b) acc[a][b] = floatx4{0.f, 0.f, 0.f, 0.f};
        for (int kk = 0; kk < 8; ++kk) {
            short8 ah0 = *(const short8*)&As_hi[((kk * 2 + 0) * 64 + lane) * 8];
            short8 al0 = *(const short8*)&As_lo[((kk * 2 + 0) * 64 + lane) * 8];
            short8 ah1 = *(const short8*)&As_hi[((kk * 2 + 1) * 64 + lane) * 8];
            short8 al1 = *(const short8*)&As_lo[((kk * 2 + 1) * 64 + lane) * 8];
#pragma unroll
            for (int q = 0; q < 4; ++q) {
                int nt = wid * 4 + q;
                size_t off = (((size_t)(k * 8 + kk) * 16 + nt) * 64 + lane) * 8;
                short8 bh = *(const short8*)&Whi[off];   // B direct global->VGPR (used once)
                short8 bl = *(const short8*)&Wlo[off];
                acc[0][q] = __builtin_amdgcn_mfma_f32_16x16x32_bf16(ah0, bh, acc[0][q], 0, 0, 0);
                acc[0][q] = __builtin_amdgcn_mfma_f32_16x16x32_bf16(al0, bh, acc[0][q], 0, 0, 0);
                acc[0][q] = __builtin_amdgcn_mfma_f32_16x16x32_bf16(ah0, bl, acc[0][q], 0, 0, 0);
                acc[1][q] = __builtin_amdgcn_mfma_f32_16x16x32_bf16(ah1, bh, acc[1][q], 0, 0, 0);
                acc[1][q] = __builtin_amdgcn_mfma_f32_16x16x32_bf16(al1, bh, acc[1][q], 0, 0, 0);
                acc[1][q] = __builtin_amdgcn_mfma_f32_16x16x32_bf16(ah1, bl, acc[1][q], 0, 0, 0);
            }
        }
        // ---- epilogue: atomic accumulate ----
        int r0 = (lane >> 4) * 4, c0 = lane & 15;
#pragma unroll
        for (int mt = 0; mt < 2; ++mt)
#pragma unroll
            for (int rr = 0; rr < 4; ++rr) {
                int row = mt * 16 + r0 + rr;
                int i = ii[row];
                if (i >= 0) {
#pragma unroll
                    for (int q = 0; q < 4; ++q)
                        atomicAdd(&out[(size_t)i * CH + wid * 64 + q * 16 + c0], acc[mt][q][rr]);
                }
            }
        __syncthreads();
    }
}

// ---------------- layer 4: 256 -> 2 ----------------
__device__ inline float wave_sum(float v) {
    for (int off = 32; off; off >>= 1) v += __shfl_xor(v, off);
    return v;
}

__global__ void dense4_k(const float* __restrict__ x, const float* __restrict__ Wc,
                         float* __restrict__ out, int n) {
    int wid = threadIdx.x >> 6, lane = threadIdx.x & 63;
    int i = blockIdx.x * 4 + wid;
    if (i >= n) return;
    floatx4 xv = *reinterpret_cast<const floatx4*>(x + (size_t)i * CH + lane * 4);
    floatx4 w0 = *reinterpret_cast<const floatx4*>(Wc + lane * 8);
    floatx4 w1 = *reinterpret_cast<const floatx4*>(Wc + lane * 8 + 4);
    float a0 = xv.x * w0.x + xv.y * w0.z + xv.z * w1.x + xv.w * w1.z;
    float a1 = xv.x * w0.y + xv.y * w0.w + xv.z * w1.y + xv.w * w1.w;
    a0 = wave_sum(a0);
    a1 = wave_sum(a1);
    if (lane == 0) { out[2 * i] = a0; out[2 * i + 1] = a1; }
}

__global__ void sparse4b_k(const float* __restrict__ x, const float* __restrict__ W4,
                           float* __restrict__ out, const int2* __restrict__ buckets,
                           const int2* __restrict__ desc, const int* __restrict__ nchunks) {
    int nc = *nchunks;
    int wid = threadIdx.x >> 6, lane = threadIdx.x & 63;
    for (int m = blockIdx.x; m < nc; m += gridDim.x) {
        int2 d = desc[m];
        int k = d.y >> 8, len = d.y & 255;
        const float* Wk = W4 + (size_t)k * CH * 2;
        floatx4 w0 = *reinterpret_cast<const floatx4*>(Wk + lane * 8);
        floatx4 w1 = *reinterpret_cast<const floatx4*>(Wk + lane * 8 + 4);
        for (int p = wid; p < len; p += 4) {
            int2 pr = buckets[d.x + p];
            floatx4 xv = *reinterpret_cast<const floatx4*>(x + (size_t)pr.y * CH + lane * 4);
            float a0 = xv.x * w0.x + xv.y * w0.z + xv.z * w1.x + xv.w * w1.z;
            float a1 = xv.x * w0.y + xv.y * w0.w + xv.z * w1.y + xv.w * w1.w;
            a0 = wave_sum(a0);
            a1 = wave_sum(a1);
            if (lane == 0) {
                atomicAdd(&out[2 * pr.x], a0);
                atomicAdd(&out[2 * pr.x + 1], a1);
            }
        }
    }
}

extern "C" void kernel_launch(void* const* d_in, const int* in_sizes, int n_in,
                              void* d_out, int out_size, void* d_ws, size_t ws_size,
                              hipStream_t stream) {
    const int* coords = (const int*)d_in[0];
    const float* feats = (const float*)d_in[1];
    const float* W1 = (const float*)d_in[2];
    const float* W2 = (const float*)d_in[3];
    const float* W3 = (const float*)d_in[4];
    const float* W4 = (const float*)d_in[5];
    float* out = (float*)d_out;
    int n = in_sizes[0] / 3;

    char* ws = (char*)d_ws;
    auto alloc = [&](size_t bytes) -> void* {
        void* p = (void*)ws;
        ws += (bytes + 255) & ~(size_t)255;
        return p;
    };
    ull* tbl = (ull*)alloc((size_t)HASH_SIZE * 8);
    unsigned* bm = (unsigned*)alloc((size_t)BM_WORDS * 4);
    unsigned* keys = (unsigned*)alloc((size_t)n * 4);
    int* kcount = (int*)alloc(27 * 4);
    int* nchunks = (int*)alloc(4);
    int ndesc = 27 * ((n + PCH - 1) / PCH);
    int2* desc = (int2*)alloc(sizeof(int2) * (size_t)ndesc);
    int2* buckets = (int2*)alloc(sizeof(int2) * 27 * (size_t)n);
    unsigned short* Whi2 = (unsigned short*)alloc((size_t)27 * 65536 * 2);
    unsigned short* Wlo2 = (unsigned short*)alloc((size_t)27 * 65536 * 2);
    unsigned short* Whi3 = (unsigned short*)alloc((size_t)27 * 65536 * 2);
    unsigned short* Wlo3 = (unsigned short*)alloc((size_t)27 * 65536 * 2);
    float* x1 = (float*)alloc((size_t)n * CH * 4);
    float* x2 = (float*)alloc((size_t)n * CH * 4);

    hipMemsetAsync(tbl, 0xFF, (size_t)HASH_SIZE * 8, stream);
    hipMemsetAsync(bm, 0, (size_t)BM_WORDS * 4, stream);
    hipMemsetAsync(kcount, 0, 27 * 4, stream);

    hash_insert_k<<<(n + 255) / 256, 256, 0, stream>>>(coords, n, tbl, keys, bm);
    neighbor_bm_k<<<(n * 9 + 255) / 256, 256, 0, stream>>>(keys, n, bm, tbl, buckets, kcount);
    chunk_desc_k<<<1, 256, 0, stream>>>(kcount, n, desc, nchunks);
    prep_w_all_k<<<(27 * 65536) / 256, 256, 0, stream>>>(W2, Whi2, Wlo2);
    prep_w_all_k<<<(27 * 65536) / 256, 256, 0, stream>>>(W3, Whi3, Wlo3);

    int mtiles = (n + 63) / 64;

    // layer 1: 2 -> 256
    dense1_k<<<(n * CH + 255) / 256, 256, 0, stream>>>(feats, W1 + 13 * 2 * CH, x1, n);
    sparse1b_k<<<1024, 256, 0, stream>>>(feats, W1, x1, buckets, desc, nchunks);

    // layer 2: 256 -> 256
    dense_mid_mfma_k<<<mtiles, 256, 0, stream>>>(x1, Whi2 + (size_t)13 * 65536,
                                                 Wlo2 + (size_t)13 * 65536, x2, n);
    sparse_mid_mfma_k<<<512, 256, 0, stream>>>(x1, Whi2, Wlo2, x2, buckets, desc, nchunks);

    // layer 3: 256 -> 256
    dense_mid_mfma_k<<<mtiles, 256, 0, stream>>>(x2, Whi3 + (size_t)13 * 65536,
                                                 Wlo3 + (size_t)13 * 65536, x1, n);
    sparse_mid_mfma_k<<<512, 256, 0, stream>>>(x2, Whi3, Wlo3, x1, buckets, desc, nchunks);

    // layer 4: 256 -> 2
    dense4_k<<<(n + 3) / 4, 256, 0, stream>>>(x1, W4 + 13 * CH * 2, out, n);
    sparse4b_k<<<512, 256, 0, stream>>>(x1, W4, out, buckets, desc, nchunks);
}

// Round 6
// 335.674 us; speedup vs baseline: 1.3734x; 1.1614x over previous
//
#include <hip/hip_runtime.h>

#define HASH_BITS 19
#define HASH_SIZE (1u << HASH_BITS)
#define HASH_MASK (HASH_SIZE - 1)
#define EMPTY64 0xFFFFFFFFFFFFFFFFull
#define CH 256
#define PCH 32       // pairs per chunk in bucketed sparse kernels
#define NREP 8       // counter/bucket replicas (atomic de-contention)
#define NSEG (27 * NREP)
#define SEGCAP 4096  // pairs per (k,rep) segment
#define BM_WORDS 536704  // ceil(258^3 / 32), padded

typedef __attribute__((ext_vector_type(8))) short short8;
typedef __attribute__((ext_vector_type(4))) float floatx4;
typedef unsigned long long ull;

// split fp32 -> bf16 hi + bf16 lo (x ~= hi + lo, each RTN-even)
__device__ inline void bf16_split(float x, unsigned short& hi, unsigned short& lo) {
    unsigned u = __float_as_uint(x);
    unsigned r = u + (0x7FFFu + ((u >> 16) & 1u));
    hi = (unsigned short)(r >> 16);
    float hif = __uint_as_float(((unsigned)hi) << 16);
    float res = x - hif;
    unsigned v = __float_as_uint(res);
    unsigned rv = v + (0x7FFFu + ((v >> 16) & 1u));
    lo = (unsigned short)(rv >> 16);
}

__device__ inline void split8_pack(const float* xa, uint4& hv, uint4& lv) {
    unsigned short h[8], l[8];
#pragma unroll
    for (int q = 0; q < 8; ++q) bf16_split(xa[q], h[q], l[q]);
    hv.x = (unsigned)h[0] | ((unsigned)h[1] << 16);
    hv.y = (unsigned)h[2] | ((unsigned)h[3] << 16);
    hv.z = (unsigned)h[4] | ((unsigned)h[5] << 16);
    hv.w = (unsigned)h[6] | ((unsigned)h[7] << 16);
    lv.x = (unsigned)l[0] | ((unsigned)l[1] << 16);
    lv.y = (unsigned)l[2] | ((unsigned)l[3] << 16);
    lv.z = (unsigned)l[4] | ((unsigned)l[5] << 16);
    lv.w = (unsigned)l[6] | ((unsigned)l[7] << 16);
}

// ---------------- hash build: fused (key<<32 | idx) single-load table ----------------
__global__ void hash_insert_k(const int* __restrict__ coords, int n,
                              ull* __restrict__ tbl, unsigned* __restrict__ keys,
                              unsigned* __restrict__ bm) {
    int i = blockIdx.x * blockDim.x + threadIdx.x;
    if (i >= n) return;
    unsigned cx = (unsigned)(coords[3 * i + 0] + 1);
    unsigned cy = (unsigned)(coords[3 * i + 1] + 1);
    unsigned cz = (unsigned)(coords[3 * i + 2] + 1);
    unsigned key = (cx * 258u + cy) * 258u + cz;
    keys[i] = key;
    atomicOr(&bm[key >> 5], 1u << (key & 31));
    ull e = ((ull)key << 32) | (unsigned)i;
    unsigned h = (key * 2654435761u) & HASH_MASK;
    while (true) {
        ull prev = atomicCAS(&tbl[h], EMPTY64, e);
        if (prev == EMPTY64) return;
        h = (h + 1) & HASH_MASK;
    }
}

// ---------------- neighbor pairs: bitmap prefilter, replicated counters ----------------
// kcnt layout: one int per 64B line, index (k*NREP + rep) * 16
__global__ void neighbor_bm_k(const unsigned* __restrict__ keys, int n,
                              const unsigned* __restrict__ bm,
                              const ull* __restrict__ tbl,
                              int2* __restrict__ buckets, int* __restrict__ kcnt) {
    int t = blockIdx.x * blockDim.x + threadIdx.x;
    if (t >= n * 9) return;
    int rep = blockIdx.x & (NREP - 1);
    int i = t / 9, r = t - i * 9;            // r = (dx+1)*3 + (dy+1)
    unsigned key = keys[i];
    int base = (int)key + ((r / 3 - 1) * 258 + (r % 3 - 1)) * 258;
    unsigned bA = base - 1, bB = base, bC = base + 1;
    unsigned hit0 = (bm[bA >> 5] >> (bA & 31)) & 1u;
    unsigned hit1 = (bm[bB >> 5] >> (bB & 31)) & 1u;
    unsigned hit2 = (bm[bC >> 5] >> (bC & 31)) & 1u;
#pragma unroll
    for (int dz = -1; dz <= 1; ++dz) {
        if (r == 4 && dz == 0) continue;     // center handled densely
        unsigned hit = dz < 0 ? hit0 : (dz == 0 ? hit1 : hit2);
        if (!hit) continue;
        unsigned nk = (unsigned)(base + dz);
        unsigned h = (nk * 2654435761u) & HASH_MASK;
        int j = -1;
        while (true) {
            ull e = tbl[h];
            if ((unsigned)(e >> 32) == nk) { j = (int)(e & 0xFFFFFFFFu); break; }
            if (e == EMPTY64) break;
            h = (h + 1) & HASH_MASK;
        }
        if (j >= 0) {
            int kk = 3 * r + dz + 1;
            int seg = kk * NREP + rep;
            int pos = atomicAdd(&kcnt[seg * 16], 1);
            buckets[(size_t)seg * SEGCAP + pos] = make_int2(i, j);
        }
    }
}

// ---------------- chunk descriptors over NSEG segments ----------------
__global__ void chunk_desc_k(const int* __restrict__ kcnt,
                             int2* __restrict__ desc, int* __restrict__ nchunks) {
    __shared__ int cnts[NSEG];
    __shared__ int offs[NSEG + 1];
    int t = threadIdx.x;
    if (t < NSEG) cnts[t] = kcnt[t * 16];
    __syncthreads();
    if (t == 0) {
        int acc = 0;
        for (int s = 0; s < NSEG; ++s) { offs[s] = acc; acc += (cnts[s] + PCH - 1) / PCH; }
        offs[NSEG] = acc;
        *nchunks = acc;
    }
    __syncthreads();
    if (t < NSEG) {
        int cnt = cnts[t];
        int o = offs[t];
        int k = t / NREP;
        for (int c = 0; c * PCH < cnt; ++c) {
            int len = min(PCH, cnt - c * PCH);
            desc[o + c] = make_int2(t * SEGCAP + c * PCH, (k << 8) | len);
        }
    }
}

// ---------------- pre-split ALL 27 W slices into MFMA-fragment-ordered bf16 image ----------
// image layout: [k(27)][kk(8)][nt(16)][lane(64)][j(8)] shorts
// cin = kk*32 + (lane>>4)*8 + j,  cout = nt*16 + (lane&15)
__global__ void prep_w_all_k(const float* __restrict__ W, unsigned short* __restrict__ Whi,
                             unsigned short* __restrict__ Wlo) {
    int tt = blockIdx.x * 256 + threadIdx.x;
    if (tt >= 27 * 65536) return;
    int k = tt >> 16, rem = tt & 65535, cin = rem >> 8, cout = rem & 255;
    float w = W[tt];
    unsigned short hb, lb;
    bf16_split(w, hb, lb);
    int kk = cin >> 5, kg = (cin >> 3) & 3, j = cin & 7, nt = cout >> 4, lc = cout & 15;
    size_t idx = ((((size_t)(k * 8 + kk) * 16 + nt) * 64) + kg * 16 + lc) * 8 + j;
    Whi[idx] = hb;
    Wlo[idx] = lb;
}

// ---------------- layer 1: Cin=2 -> 256, dense center ----------------
__global__ void dense1_k(const float* __restrict__ x, const float* __restrict__ Wc,
                         float* __restrict__ out, int n) {
    int t = blockIdx.x * blockDim.x + threadIdx.x;
    if (t >= n * CH) return;
    int i = t >> 8, co = t & 255;
    float2 xv = *reinterpret_cast<const float2*>(x + 2 * i);
    out[t] = fmaf(xv.x, Wc[co], xv.y * Wc[CH + co]);
}

__global__ void sparse1b_k(const float* __restrict__ feats, const float* __restrict__ W1,
                           float* __restrict__ out, const int2* __restrict__ buckets,
                           const int2* __restrict__ desc, const int* __restrict__ nchunks) {
    __shared__ float xs[PCH][2];
    __shared__ int ii[PCH];
    int nc = *nchunks;
    int t = threadIdx.x;
    for (int m = blockIdx.x; m < nc; m += gridDim.x) {
        int2 d = desc[m];
        int k = d.y >> 8, len = d.y & 255;
        if (t < PCH) {
            if (t < len) {
                int2 pr = buckets[d.x + t];
                ii[t] = pr.x;
                xs[t][0] = feats[2 * pr.y];
                xs[t][1] = feats[2 * pr.y + 1];
            } else {
                ii[t] = -1;
                xs[t][0] = 0.f; xs[t][1] = 0.f;
            }
        }
        __syncthreads();
        const float* Wk = W1 + (size_t)k * 2 * CH;
        float w0 = Wk[t], w1 = Wk[CH + t];
#pragma unroll
        for (int p = 0; p < PCH; ++p) {
            int i = ii[p];
            if (i >= 0) atomicAdd(&out[(size_t)i * CH + t], fmaf(xs[p][0], w0, xs[p][1] * w1));
        }
        __syncthreads();
    }
}

// ---------------- mid layers dense center: A-LDS dbuf + B reg-dbuf, 1 barrier/kk ----------
__global__ __launch_bounds__(256, 2) void dense_mid_mfma_k(
        const float* __restrict__ x,
        const unsigned short* __restrict__ Whi,
        const unsigned short* __restrict__ Wlo,
        float* __restrict__ out, int n) {
    __shared__ unsigned short AsH0[2048], AsL0[2048];  // [mt(4)][flane(64)][j(8)]
    __shared__ unsigned short AsH1[2048], AsL1[2048];
    int t = threadIdx.x;
    int wid = t >> 6, lane = t & 63;
    int i0 = blockIdx.x * 64;

    floatx4 acc[4][4];
#pragma unroll
    for (int a = 0; a < 4; ++a)
#pragma unroll
        for (int b = 0; b < 4; ++b) acc[a][b] = floatx4{0.f, 0.f, 0.f, 0.f};

    // A staging role: thread t stages row ar, k-group akg
    int ar = t >> 2, akg = t & 3;
    int abase = ((ar >> 4) * 64 + akg * 16 + (ar & 15)) * 8;
    int rowi = i0 + ar;
    float okf = (rowi < n) ? 1.f : 0.f;
    const float* xrow = x + (size_t)min(rowi, n - 1) * CH + akg * 8;

    short8 Bh0[4], Bl0[4], Bh1[4], Bl1[4];

    auto loadB = [&](int kk, short8* Bh, short8* Bl) {
#pragma unroll
        for (int q = 0; q < 4; ++q) {
            size_t off = (((size_t)kk * 16 + wid * 4 + q) * 64 + lane) * 8;
            Bh[q] = *(const short8*)&Whi[off];
            Bl[q] = *(const short8*)&Wlo[off];
        }
    };
    auto stageA = [&](int kk, unsigned short* AH, unsigned short* AL) {
        floatx4 v0 = *(const floatx4*)(xrow + kk * 32);
        floatx4 v1 = *(const floatx4*)(xrow + kk * 32 + 4);
        float xa[8];
        xa[0] = v0.x * okf; xa[1] = v0.y * okf; xa[2] = v0.z * okf; xa[3] = v0.w * okf;
        xa[4] = v1.x * okf; xa[5] = v1.y * okf; xa[6] = v1.z * okf; xa[7] = v1.w * okf;
        uint4 hv, lv;
        split8_pack(xa, hv, lv);
        *(uint4*)&AH[abase] = hv;
        *(uint4*)&AL[abase] = lv;
    };
    auto compute = [&](unsigned short* AH, unsigned short* AL, short8* Bh, short8* Bl) {
#pragma unroll
        for (int mt = 0; mt < 4; ++mt) {
            short8 ah = *(const short8*)&AH[(mt * 64 + lane) * 8];
            short8 al = *(const short8*)&AL[(mt * 64 + lane) * 8];
#pragma unroll
            for (int q = 0; q < 4; ++q) {
                acc[mt][q] = __builtin_amdgcn_mfma_f32_16x16x32_bf16(ah, Bh[q], acc[mt][q], 0, 0, 0);
                acc[mt][q] = __builtin_amdgcn_mfma_f32_16x16x32_bf16(al, Bh[q], acc[mt][q], 0, 0, 0);
                acc[mt][q] = __builtin_amdgcn_mfma_f32_16x16x32_bf16(ah, Bl[q], acc[mt][q], 0, 0, 0);
            }
        }
    };

    // prologue: B(0) + A(0)
    loadB(0, Bh0, Bl0);
    stageA(0, AsH0, AsL0);
    __syncthreads();

#pragma unroll
    for (int kk2 = 0; kk2 < 8; kk2 += 2) {
        if (kk2 + 1 < 8) {
            loadB(kk2 + 1, Bh1, Bl1);
            stageA(kk2 + 1, AsH1, AsL1);
        }
        compute(AsH0, AsL0, Bh0, Bl0);
        __syncthreads();
        if (kk2 + 2 < 8) {
            loadB(kk2 + 2, Bh0, Bl0);
            stageA(kk2 + 2, AsH0, AsL0);
        }
        compute(AsH1, AsL1, Bh1, Bl1);
        __syncthreads();
    }

    // epilogue: D row=(lane>>4)*4+reg, col=lane&15
    int r0 = (lane >> 4) * 4, c0 = lane & 15;
#pragma unroll
    for (int mt = 0; mt < 4; ++mt)
#pragma unroll
        for (int r = 0; r < 4; ++r) {
            int row = i0 + mt * 16 + r0 + r;
            if (row < n) {
#pragma unroll
                for (int q = 0; q < 4; ++q)
                    out[(size_t)row * CH + wid * 64 + q * 16 + c0] = acc[mt][q][r];
            }
        }
}

// ---------------- mid layers sparse: 32 gathered rows per chunk, 3-pass MFMA ----------------
__global__ __launch_bounds__(256) void sparse_mid_mfma_k(
        const float* __restrict__ x,
        const unsigned short* __restrict__ Whi,
        const unsigned short* __restrict__ Wlo,
        float* __restrict__ out, const int2* __restrict__ buckets,
        const int2* __restrict__ desc, const int* __restrict__ nchunks) {
    // A image: [kk(8)][mt(2)][lane(64)][j(8)]
    __shared__ unsigned short As_hi[8192];
    __shared__ unsigned short As_lo[8192];
    __shared__ int ii[PCH];
    int nc = *nchunks;
    int t = threadIdx.x;
    int wid = t >> 6, lane = t & 63;
    int r = t >> 3, kk0 = t & 7;          // 8 threads per gathered row
    int mt_s = r >> 4, rl = r & 15;
    for (int m = blockIdx.x; m < nc; m += gridDim.x) {
        int2 d = desc[m];
        int k = d.y >> 8, len = d.y & 255;
        // ---- stage A (full K=256 for 32 rows), split hi/lo ----
        if (r < len) {
            int2 pr = buckets[d.x + r];
            if (kk0 == 0) ii[r] = pr.x;
            const float* src = x + (size_t)pr.y * CH + kk0 * 32;
#pragma unroll
            for (int kg = 0; kg < 4; ++kg) {
                float xa[8];
                floatx4 v0 = *(const floatx4*)(src + kg * 8);
                floatx4 v1 = *(const floatx4*)(src + kg * 8 + 4);
                xa[0] = v0.x; xa[1] = v0.y; xa[2] = v0.z; xa[3] = v0.w;
                xa[4] = v1.x; xa[5] = v1.y; xa[6] = v1.z; xa[7] = v1.w;
                uint4 hv, lv;
                split8_pack(xa, hv, lv);
                int ab = ((kk0 * 2 + mt_s) * 64 + kg * 16 + rl) * 8;
                *(uint4*)&As_hi[ab] = hv;
                *(uint4*)&As_lo[ab] = lv;
            }
        } else {
            if (kk0 == 0) ii[r] = -1;
            uint4 z = {0, 0, 0, 0};
#pragma unroll
            for (int kg = 0; kg < 4; ++kg) {
                int ab = ((kk0 * 2 + mt_s) * 64 + kg * 16 + rl) * 8;
                *(uint4*)&As_hi[ab] = z;
                *(uint4*)&As_lo[ab] = z;
            }
        }
        __syncthreads();
        floatx4 acc[2][4];
#pragma unroll
        for (int a = 0; a < 2; ++a)
#pragma unroll
            for (int b = 0; b < 4; ++b) acc[a][b] = floatx4{0.f, 0.f, 0.f, 0.f};
        for (int kk = 0; kk < 8; ++kk) {
            short8 ah0 = *(const short8*)&As_hi[((kk * 2 + 0) * 64 + lane) * 8];
            short8 al0 = *(const short8*)&As_lo[((kk * 2 + 0) * 64 + lane) * 8];
            short8 ah1 = *(const short8*)&As_hi[((kk * 2 + 1) * 64 + lane) * 8];
            short8 al1 = *(const short8*)&As_lo[((kk * 2 + 1) * 64 + lane) * 8];
#pragma unroll
            for (int q = 0; q < 4; ++q) {
                int nt = wid * 4 + q;
                size_t off = (((size_t)(k * 8 + kk) * 16 + nt) * 64 + lane) * 8;
                short8 bh = *(const short8*)&Whi[off];   // B direct global->VGPR (used once)
                short8 bl = *(const short8*)&Wlo[off];
                acc[0][q] = __builtin_amdgcn_mfma_f32_16x16x32_bf16(ah0, bh, acc[0][q], 0, 0, 0);
                acc[0][q] = __builtin_amdgcn_mfma_f32_16x16x32_bf16(al0, bh, acc[0][q], 0, 0, 0);
                acc[0][q] = __builtin_amdgcn_mfma_f32_16x16x32_bf16(ah0, bl, acc[0][q], 0, 0, 0);
                acc[1][q] = __builtin_amdgcn_mfma_f32_16x16x32_bf16(ah1, bh, acc[1][q], 0, 0, 0);
                acc[1][q] = __builtin_amdgcn_mfma_f32_16x16x32_bf16(al1, bh, acc[1][q], 0, 0, 0);
                acc[1][q] = __builtin_amdgcn_mfma_f32_16x16x32_bf16(ah1, bl, acc[1][q], 0, 0, 0);
            }
        }
        // ---- epilogue: atomic accumulate ----
        int r0 = (lane >> 4) * 4, c0 = lane & 15;
#pragma unroll
        for (int mt = 0; mt < 2; ++mt)
#pragma unroll
            for (int rr = 0; rr < 4; ++rr) {
                int row = mt * 16 + r0 + rr;
                int i = ii[row];
                if (i >= 0) {
#pragma unroll
                    for (int q = 0; q < 4; ++q)
                        atomicAdd(&out[(size_t)i * CH + wid * 64 + q * 16 + c0], acc[mt][q][rr]);
                }
            }
        __syncthreads();
    }
}

// ---------------- layer 4: 256 -> 2 ----------------
__device__ inline float wave_sum(float v) {
    for (int off = 32; off; off >>= 1) v += __shfl_xor(v, off);
    return v;
}

__global__ void dense4_k(const float* __restrict__ x, const float* __restrict__ Wc,
                         float* __restrict__ out, int n) {
    int wid = threadIdx.x >> 6, lane = threadIdx.x & 63;
    int i = blockIdx.x * 4 + wid;
    if (i >= n) return;
    floatx4 xv = *reinterpret_cast<const floatx4*>(x + (size_t)i * CH + lane * 4);
    floatx4 w0 = *reinterpret_cast<const floatx4*>(Wc + lane * 8);
    floatx4 w1 = *reinterpret_cast<const floatx4*>(Wc + lane * 8 + 4);
    float a0 = xv.x * w0.x + xv.y * w0.z + xv.z * w1.x + xv.w * w1.z;
    float a1 = xv.x * w0.y + xv.y * w0.w + xv.z * w1.y + xv.w * w1.w;
    a0 = wave_sum(a0);
    a1 = wave_sum(a1);
    if (lane == 0) { out[2 * i] = a0; out[2 * i + 1] = a1; }
}

__global__ void sparse4b_k(const float* __restrict__ x, const float* __restrict__ W4,
                           float* __restrict__ out, const int2* __restrict__ buckets,
                           const int2* __restrict__ desc, const int* __restrict__ nchunks) {
    int nc = *nchunks;
    int wid = threadIdx.x >> 6, lane = threadIdx.x & 63;
    for (int m = blockIdx.x; m < nc; m += gridDim.x) {
        int2 d = desc[m];
        int k = d.y >> 8, len = d.y & 255;
        const float* Wk = W4 + (size_t)k * CH * 2;
        floatx4 w0 = *reinterpret_cast<const floatx4*>(Wk + lane * 8);
        floatx4 w1 = *reinterpret_cast<const floatx4*>(Wk + lane * 8 + 4);
        for (int p = wid; p < len; p += 4) {
            int2 pr = buckets[d.x + p];
            floatx4 xv = *reinterpret_cast<const floatx4*>(x + (size_t)pr.y * CH + lane * 4);
            float a0 = xv.x * w0.x + xv.y * w0.z + xv.z * w1.x + xv.w * w1.z;
            float a1 = xv.x * w0.y + xv.y * w0.w + xv.z * w1.y + xv.w * w1.w;
            a0 = wave_sum(a0);
            a1 = wave_sum(a1);
            if (lane == 0) {
                atomicAdd(&out[2 * pr.x], a0);
                atomicAdd(&out[2 * pr.x + 1], a1);
            }
        }
    }
}

extern "C" void kernel_launch(void* const* d_in, const int* in_sizes, int n_in,
                              void* d_out, int out_size, void* d_ws, size_t ws_size,
                              hipStream_t stream) {
    const int* coords = (const int*)d_in[0];
    const float* feats = (const float*)d_in[1];
    const float* W1 = (const float*)d_in[2];
    const float* W2 = (const float*)d_in[3];
    const float* W3 = (const float*)d_in[4];
    const float* W4 = (const float*)d_in[5];
    float* out = (float*)d_out;
    int n = in_sizes[0] / 3;

    char* ws = (char*)d_ws;
    auto alloc = [&](size_t bytes) -> void* {
        void* p = (void*)ws;
        ws += (bytes + 255) & ~(size_t)255;
        return p;
    };
    ull* tbl = (ull*)alloc((size_t)HASH_SIZE * 8);
    unsigned* bm = (unsigned*)alloc((size_t)BM_WORDS * 4);
    unsigned* keys = (unsigned*)alloc((size_t)n * 4);
    int* kcnt = (int*)alloc((size_t)NSEG * 16 * 4);   // 1 counter per 64B line
    int* nchunks = (int*)alloc(4);
    int ndesc = NSEG * (SEGCAP / PCH);
    int2* desc = (int2*)alloc(sizeof(int2) * (size_t)ndesc);
    int2* buckets = (int2*)alloc(sizeof(int2) * (size_t)NSEG * SEGCAP);
    unsigned short* Whi2 = (unsigned short*)alloc((size_t)27 * 65536 * 2);
    unsigned short* Wlo2 = (unsigned short*)alloc((size_t)27 * 65536 * 2);
    unsigned short* Whi3 = (unsigned short*)alloc((size_t)27 * 65536 * 2);
    unsigned short* Wlo3 = (unsigned short*)alloc((size_t)27 * 65536 * 2);
    float* x1 = (float*)alloc((size_t)n * CH * 4);
    float* x2 = (float*)alloc((size_t)n * CH * 4);

    hipMemsetAsync(tbl, 0xFF, (size_t)HASH_SIZE * 8, stream);
    hipMemsetAsync(bm, 0, (size_t)BM_WORDS * 4, stream);
    hipMemsetAsync(kcnt, 0, (size_t)NSEG * 16 * 4, stream);

    hash_insert_k<<<(n + 255) / 256, 256, 0, stream>>>(coords, n, tbl, keys, bm);
    neighbor_bm_k<<<(n * 9 + 255) / 256, 256, 0, stream>>>(keys, n, bm, tbl, buckets, kcnt);
    chunk_desc_k<<<1, 256, 0, stream>>>(kcnt, desc, nchunks);
    prep_w_all_k<<<(27 * 65536) / 256, 256, 0, stream>>>(W2, Whi2, Wlo2);
    prep_w_all_k<<<(27 * 65536) / 256, 256, 0, stream>>>(W3, Whi3, Wlo3);

    int mtiles = (n + 63) / 64;

    // layer 1: 2 -> 256
    dense1_k<<<(n * CH + 255) / 256, 256, 0, stream>>>(feats, W1 + 13 * 2 * CH, x1, n);
    sparse1b_k<<<1024, 256, 0, stream>>>(feats, W1, x1, buckets, desc, nchunks);

    // layer 2: 256 -> 256
    dense_mid_mfma_k<<<mtiles, 256, 0, stream>>>(x1, Whi2 + (size_t)13 * 65536,
                                                 Wlo2 + (size_t)13 * 65536, x2, n);
    sparse_mid_mfma_k<<<512, 256, 0, stream>>>(x1, Whi2, Wlo2, x2, buckets, desc, nchunks);

    // layer 3: 256 -> 256
    dense_mid_mfma_k<<<mtiles, 256, 0, stream>>>(x2, Whi3 + (size_t)13 * 65536,
                                                 Wlo3 + (size_t)13 * 65536, x1, n);
    sparse_mid_mfma_k<<<512, 256, 0, stream>>>(x2, Whi3, Wlo3, x1, buckets, desc, nchunks);

    // layer 4: 256 -> 2
    dense4_k<<<(n + 3) / 4, 256, 0, stream>>>(x1, W4 + 13 * CH * 2, out, n);
    sparse4b_k<<<512, 256, 0, stream>>>(x1, W4, out, buckets, desc, nchunks);
}